// Round 1
// baseline (143.639 us; speedup 1.0000x reference)
//
#include <hip/hip_runtime.h>
#include <math.h>

// Problem constants (from reference)
constexpr int NH = 778;            // hand verts per batch
constexpr int BLK = 128;           // threads per block (2 waves)
constexpr int NSLOT = 6;           // hand points per thread: 128*6 = 768
constexpr int CHUNK = 313;         // obj points per block chunk (ceil(40000/128))

// Kernel 1: per-(batch, obj-chunk) block computes running min squared distance
// from every hand vertex to the obj points in its chunk, then atomicMin's
// into the global [B,778] min-d2 buffer (uint bit-pattern ordering, valid
// for non-negative floats).
__global__ __launch_bounds__(BLK) void nn_min_kernel(
    const float* __restrict__ hand,   // [B, NH, 3]
    const float* __restrict__ obj,    // [B, V, 3]
    unsigned int* __restrict__ minb,  // [B, NH] bits of min d2
    int V)
{
    __shared__ float s_obj[CHUNK * 3];
    const int b   = blockIdx.y;
    const int c   = blockIdx.x;
    const int tid = threadIdx.x;
    const int j0  = c * CHUNK;
    const int cnt = min(CHUNK, V - j0);

    // cooperative, coalesced load of this block's obj chunk into LDS
    const float* op = obj + (size_t)b * V * 3 + (size_t)j0 * 3;
    for (int i = tid; i < cnt * 3; i += BLK) s_obj[i] = op[i];
    __syncthreads();

    // each thread owns 6 hand points in registers
    const float* hb = hand + (size_t)b * NH * 3;
    float hx[NSLOT], hy[NSLOT], hz[NSLOT], m[NSLOT];
#pragma unroll
    for (int s = 0; s < NSLOT; ++s) {
        const int h = tid + s * BLK;   // < 768 always
        hx[s] = hb[h * 3 + 0];
        hy[s] = hb[h * 3 + 1];
        hz[s] = hb[h * 3 + 2];
        m[s]  = 3.4e38f;
    }

    for (int j = 0; j < cnt; ++j) {
        // same address for all lanes -> LDS broadcast, conflict-free
        const float ox = s_obj[3 * j + 0];
        const float oy = s_obj[3 * j + 1];
        const float oz = s_obj[3 * j + 2];
#pragma unroll
        for (int s = 0; s < NSLOT; ++s) {
            const float dx = hx[s] - ox;
            const float dy = hy[s] - oy;
            const float dz = hz[s] - oz;
            const float d2 = dx * dx + dy * dy + dz * dz;  // fma-contracted
            m[s] = fminf(m[s], d2);
        }
    }

#pragma unroll
    for (int s = 0; s < NSLOT; ++s) {
        const int h = tid + s * BLK;
        atomicMin(&minb[b * NH + h], __float_as_uint(m[s]));
    }

    // tail: hand points 768..777 handled by lanes 0..9 (wave 0 only)
    if (tid < NH - NSLOT * BLK) {
        const int h = NSLOT * BLK + tid;
        const float tx = hb[h * 3 + 0];
        const float ty = hb[h * 3 + 1];
        const float tz = hb[h * 3 + 2];
        float tm = 3.4e38f;
        for (int j = 0; j < cnt; ++j) {
            const float dx = tx - s_obj[3 * j + 0];
            const float dy = ty - s_obj[3 * j + 1];
            const float dz = tz - s_obj[3 * j + 2];
            const float d2 = dx * dx + dy * dy + dz * dz;
            tm = fminf(tm, d2);
        }
        atomicMin(&minb[b * NH + h], __float_as_uint(tm));
    }
}

// Kernel 2: single-block final reduction -> 6 scalar outputs
__global__ __launch_bounds__(256) void finalize_kernel(
    const unsigned int* __restrict__ minb,  // [B, NH] bits of min d2
    float* __restrict__ out, int B)
{
    constexpr float COLL = 0.005f;
    constexpr float CONT = 0.01f;
    const int total = B * NH;
    const int tid = threadIdx.x;

    double sum_d = 0.0, pen_sum = 0.0, att_sum = 0.0;
    int pen_cnt = 0, att_cnt = 0;

    for (int i = tid; i < total; i += 256) {
        const float d2 = __uint_as_float(minb[i]);
        const float d  = sqrtf(d2);
        sum_d += (double)d;
        if (d < COLL) {
            const float t = COLL - d;
            pen_sum += (double)(t * t);
            pen_cnt++;
        }
        const int n = i % NH;
        const bool isc = (n == 745) | (n == 317) | (n == 444) | (n == 556) |
                         (n == 673) | (n == 95)  | (n == 182) | (n == 234) |
                         (n == 279) | (n == 320);
        if (isc & (d > COLL) & (d < CONT)) {
            att_sum += (double)(d * d);
            att_cnt++;
        }
    }

    __shared__ double sd[256], sp[256], sa[256];
    __shared__ int    cp[256], ca[256];
    sd[tid] = sum_d; sp[tid] = pen_sum; sa[tid] = att_sum;
    cp[tid] = pen_cnt; ca[tid] = att_cnt;
    __syncthreads();
    for (int off = 128; off > 0; off >>= 1) {
        if (tid < off) {
            sd[tid] += sd[tid + off];
            sp[tid] += sp[tid + off];
            sa[tid] += sa[tid + off];
            cp[tid] += cp[tid + off];
            ca[tid] += ca[tid + off];
        }
        __syncthreads();
    }
    if (tid == 0) {
        const double pen_loss = cp[0] > 0 ? sp[0] / (double)cp[0] : 0.0;
        const double att_loss = ca[0] > 0 ? sa[0] / (double)ca[0] : 0.0;
        out[0] = (float)(100.0 * pen_loss + 10.0 * att_loss);  // contact_loss
        out[1] = (float)pen_loss;                              // pen_loss
        out[2] = (float)att_loss;                              // att_loss
        out[3] = (float)(sd[0] / (double)total);               // dist_mean
        out[4] = (float)ca[0];                                 // num_contacts
        out[5] = (float)cp[0];                                 // num_penetrations
    }
}

extern "C" void kernel_launch(void* const* d_in, const int* in_sizes, int n_in,
                              void* d_out, int out_size, void* d_ws, size_t ws_size,
                              hipStream_t stream) {
    const float* hand = (const float*)d_in[0];  // [B, 778, 3] fp32
    const float* obj  = (const float*)d_in[1];  // [B, V, 3]   fp32
    // d_in[2] (hand_faces), d_in[3] (obj_faces): unused by the loss

    const int B = in_sizes[0] / (NH * 3);
    const int V = in_sizes[1] / (B * 3);
    const int nchunks = (V + CHUNK - 1) / CHUNK;

    unsigned int* minb = (unsigned int*)d_ws;  // [B, NH] min-d2 bit patterns

    // init min buffer to 0x7F7F7F7F (~3.39e38 as float; > any real d2)
    hipMemsetAsync(d_ws, 0x7F, (size_t)B * NH * sizeof(unsigned int), stream);

    dim3 grid(nchunks, B);
    nn_min_kernel<<<grid, BLK, 0, stream>>>(hand, obj, minb, V);
    finalize_kernel<<<1, 256, 0, stream>>>(minb, (float*)d_out, B);
}